// Round 1
// baseline (6586.938 us; speedup 1.0000x reference)
//
#include <hip/hip_runtime.h>
#include <hip/hip_bf16.h>
#include <stdint.h>

// Problem constants
#define HD    256      // hidden
#define LL    50       // friend seq len
#define SS    50       // common seq len
#define NB    64       // batch
#define MAXF  32
#define NSEQ  2048     // NB*MAXF
#define MB    32       // sequences per block (one 32-row MFMA M-tile)
#define NBLK  64       // NSEQ/MB
#define XP    264      // padded LDS row (bf16 elems): 528B rows, 16B aligned

typedef __attribute__((ext_vector_type(8)))  short bf16x8;
typedef __attribute__((ext_vector_type(16))) float f32x16;
typedef __attribute__((ext_vector_type(4)))  unsigned short u16x4;

__device__ __forceinline__ f32x16 mfma32(bf16x8 a, bf16x8 b, f32x16 c) {
    return __builtin_amdgcn_mfma_f32_32x32x16_bf16(a, b, c, 0, 0, 0);
}

__device__ __forceinline__ unsigned short f2bf_rne(float f) {
    union { float f; uint32_t u; } v; v.f = f;
    uint32_t u = v.u;
    uint32_t r = u + 0x7FFFu + ((u >> 16) & 1u);
    return (unsigned short)(r >> 16);
}
__device__ __forceinline__ float bf2f(unsigned short b) {
    union { float f; uint32_t u; } v; v.u = ((uint32_t)b) << 16;
    return v.f;
}

// ---------------------------------------------------------------------------
// Pack weights -> per-wave MFMA 32x32x16 fragment stream + Wf^T.
// 8-wave layout: wpk index = ((((wv*2+l)*2 + m)*16 + ks)*6 + fr)*512 + lane*8 + j
//   fr = gate*2 + plane  (gate r/z/n, plane hi/lo)
//   W row n = gate*256 + wv*32 + (lane&31)     (wave wv owns cols [32wv,32wv+32))
//   k       = ks*16 + (lane>>5)*8 + j
// ---------------------------------------------------------------------------
__global__ void pack_kernel(const float* __restrict__ Wih0, const float* __restrict__ Whh0,
                            const float* __restrict__ Wih1, const float* __restrict__ Whh1,
                            const float* __restrict__ Wf,
                            unsigned short* __restrict__ wpk,
                            float* __restrict__ WfT) {
    int idx = blockIdx.x * blockDim.x + threadIdx.x;
    const int TOTW = 1572864;
    if (idx < TOTW) {
        int j    = idx & 7;
        int lane = (idx >> 3) & 63;
        int fr   = (idx >> 9) % 6;
        int t2   = (idx >> 9) / 6;           // ((wv*2+l)*2+m)*16+ks
        int ks   = t2 & 15;
        int m    = (t2 >> 4) & 1;
        int l    = (t2 >> 5) & 1;
        int wvv  = t2 >> 6;                  // 0..7
        int gate = fr >> 1, plane = fr & 1;
        const float* W = (l == 0) ? (m == 0 ? Wih0 : Whh0)
                                  : (m == 0 ? Wih1 : Whh1);
        int n = gate * 256 + wvv * 32 + (lane & 31);
        int k = ks * 16 + (lane >> 5) * 8 + j;
        float v = W[n * HD + k];
        unsigned short hi = f2bf_rne(v);
        wpk[idx] = plane ? f2bf_rne(v - bf2f(hi)) : hi;
    } else {
        int idx2 = idx - TOTW;
        if (idx2 < 512 * 256) {              // WfT[k][h] = Wf[h][k]
            int k = idx2 >> 8; int h = idx2 & 255;
            WfT[k * 256 + h] = Wf[h * 512 + k];
        }
    }
}

// ---------------------------------------------------------------------------
// Counting sort of the 2048 sequences by friend_len (1..50), ascending.
// ---------------------------------------------------------------------------
__global__ void sort_kernel(const int* __restrict__ flen, int* __restrict__ sid) {
    __shared__ int hist[64];
    __shared__ int offs[64];
    int tid = threadIdx.x;
    if (tid < 64) hist[tid] = 0;
    __syncthreads();
    for (int i = tid; i < NSEQ; i += blockDim.x) atomicAdd(&hist[flen[i]], 1);
    __syncthreads();
    if (tid == 0) {
        int acc = 0;
        for (int v = 1; v <= 50; v++) { offs[v] = acc; acc += hist[v]; }
    }
    __syncthreads();
    for (int i = tid; i < NSEQ; i += blockDim.x) {
        int pos = atomicAdd(&offs[flen[i]], 1);
        sid[pos] = i;
    }
}

// ---------------------------------------------------------------------------
// Fused 2-layer GRU. 512 threads = 8 waves (2 waves/SIMD for latency hiding),
// 1 block/CU (LDS-forced). Wave w owns gate columns [32w, 32w+32) of each
// gate. Split-bf16 (hi+lo) 3-term MFMA. Weight stream 4-buffer rotated
// (lookahead 3 batches). Hidden carry reconstructed from LDS hi+lo planes.
// ---------------------------------------------------------------------------
__global__ __launch_bounds__(512) __attribute__((amdgpu_waves_per_eu(2)))
void gru_kernel(const float* __restrict__ friend_x,
                const int* __restrict__ flen,
                const int* __restrict__ sid,
                const unsigned short* __restrict__ wpk,
                const float* __restrict__ bih0, const float* __restrict__ bhh0,
                const float* __restrict__ bih1, const float* __restrict__ bhh1,
                float* __restrict__ friend_last) {
    __shared__ __align__(16) unsigned short Xhi[MB][XP],  Xlo[MB][XP];
    __shared__ __align__(16) unsigned short H0hi[MB][XP], H0lo[MB][XP];
    __shared__ __align__(16) unsigned short H1hi[MB][XP], H1lo[MB][XP];
    __shared__ int sidS[MB], lenS[MB];

    const int tid  = threadIdx.x;
    const int g    = blockIdx.x;
    const int wv   = tid >> 6;          // 0..7
    const int lane = tid & 63;
    const int l31  = lane & 31;
    const int half = lane >> 5;

    if (tid < MB) {
        int s_ = sid[g * MB + tid];
        sidS[tid] = s_;
        lenS[tid] = flen[s_];
    }
    for (int i = tid; i < MB * XP / 2; i += 512) {
        ((uint32_t*)&H0hi[0][0])[i] = 0; ((uint32_t*)&H0lo[0][0])[i] = 0;
        ((uint32_t*)&H1hi[0][0])[i] = 0; ((uint32_t*)&H1lo[0][0])[i] = 0;
    }
    __syncthreads();

    int maxlen = 0;
#pragma unroll
    for (int s = 0; s < MB; s++) maxlen = max(maxlen, lenS[s]);

    const int j0 = wv * 32 + l31;       // this lane's gate column

    // biases (acc-init values); n-gate input/hidden kept separate
    float b0R  = bih0[j0] + bhh0[j0];
    float b0Z  = bih0[256 + j0] + bhh0[256 + j0];
    float b0Ni = bih0[512 + j0];
    float b0Nh = bhh0[512 + j0];
    float b1R  = bih1[j0] + bhh1[j0];
    float b1Z  = bih1[256 + j0] + bhh1[256 + j0];
    float b1Ni = bih1[512 + j0];
    float b1Nh = bhh1[512 + j0];

    int srow[4];                        // staged sequence ids (rows wv*4..wv*4+3)
#pragma unroll
    for (int r = 0; r < 4; r++) srow[r] = sidS[wv * 4 + r];

    const int fragBase = l31 * XP + half * 8;

    auto loadB6 = [&](bf16x8* B, const unsigned short* p) {
#pragma unroll
        for (int f = 0; f < 6; f++) B[f] = *(const bf16x8*)(p + f * 512);
    };

    // 9 MFMAs: one K=16 step for this wave's 32-col subtile of all 3 gates
    auto compute9 = [&](const bf16x8* B, bf16x8 ah, bf16x8 al,
                        f32x16& aRs, f32x16& aZs, f32x16& aNs) {
        aRs = mfma32(ah, B[0], aRs);
        aRs = mfma32(al, B[0], aRs);
        aRs = mfma32(ah, B[1], aRs);
        aZs = mfma32(ah, B[2], aZs);
        aZs = mfma32(al, B[2], aZs);
        aZs = mfma32(ah, B[3], aZs);
        aNs = mfma32(ah, B[4], aNs);
        aNs = mfma32(al, B[4], aNs);
        aNs = mfma32(ah, B[5], aNs);
    };

    // one m-phase (16 K-steps) of a layer: A from (Ah,Al), weights at pm.
    // 4-buffer rotation: each batch is loaded 3 compute9s (~216cy) before use.
    auto halfMM = [&](const unsigned short* pm,
                      const unsigned short* Ah_, const unsigned short* Al_,
                      f32x16& aRs, f32x16& aZs, f32x16& aNs) {
        bf16x8 B0[6], B1[6], B2[6], B3[6];
        loadB6(B0, pm);
        loadB6(B1, pm + 3072);
        loadB6(B2, pm + 6144);
        loadB6(B3, pm + 9216);
        bf16x8 ahA = *(const bf16x8*)(Ah_ + fragBase);
        bf16x8 alA = *(const bf16x8*)(Al_ + fragBase);
        bf16x8 ahB, alB;
#pragma unroll
        for (int base = 0; base < 16; base += 4) {
            ahB = *(const bf16x8*)(Ah_ + fragBase + (base + 1) * 16);
            alB = *(const bf16x8*)(Al_ + fragBase + (base + 1) * 16);
            compute9(B0, ahA, alA, aRs, aZs, aNs);
            if (base + 4 < 16) loadB6(B0, pm + (size_t)(base + 4) * 3072);
            ahA = *(const bf16x8*)(Ah_ + fragBase + (base + 2) * 16);
            alA = *(const bf16x8*)(Al_ + fragBase + (base + 2) * 16);
            compute9(B1, ahB, alB, aRs, aZs, aNs);
            if (base + 5 < 16) loadB6(B1, pm + (size_t)(base + 5) * 3072);
            ahB = *(const bf16x8*)(Ah_ + fragBase + (base + 3) * 16);
            alB = *(const bf16x8*)(Al_ + fragBase + (base + 3) * 16);
            compute9(B2, ahA, alA, aRs, aZs, aNs);
            if (base + 6 < 16) loadB6(B2, pm + (size_t)(base + 6) * 3072);
            {
                const int kn = (base + 4 < 16) ? base + 4 : 15;  // clamped prefetch
                ahA = *(const bf16x8*)(Ah_ + fragBase + kn * 16);
                alA = *(const bf16x8*)(Al_ + fragBase + kn * 16);
            }
            compute9(B3, ahB, alB, aRs, aZs, aNs);
            if (base + 7 < 16) loadB6(B3, pm + (size_t)(base + 7) * 3072);
        }
    };

    auto initAcc = [&](f32x16& a, float b) {
        f32x16 v;
#pragma unroll
        for (int i = 0; i < 16; i++) v[i] = b;
        a = v;
    };

    // gate epilogue; C-layout: col = lane&31, row = (reg&3)+8*(reg>>2)+4*half.
    // hidden carry reconstructed as hi+lo from LDS (err ~2^-25, negligible).
    auto epi = [&](f32x16& aRs, f32x16& aZs, f32x16& aNis, f32x16& aNhs,
                   unsigned short (*Ohi)[XP], unsigned short (*Olo)[XP],
                   bool gather, int t) {
        const int j = j0;
#pragma unroll
        for (int rg = 0; rg < 16; rg++) {
            const int row = (rg & 3) + ((rg >> 2) << 3) + (half << 2);
            float hOld = bf2f(Ohi[row][j]) + bf2f(Olo[row][j]);
            float rr = 1.f / (1.f + __expf(-aRs[rg]));
            float zz = 1.f / (1.f + __expf(-aZs[rg]));
            float nx = aNis[rg] + rr * aNhs[rg];
            float e  = __expf(-2.f * fabsf(nx));
            float th = 1.f - 2.f * e / (1.f + e);
            th = (nx < 0.f) ? -th : th;
            float hNew = (1.f - zz) * th + zz * hOld;
            unsigned short hi_ = f2bf_rne(hNew);
            Ohi[row][j] = hi_;
            Olo[row][j] = f2bf_rne(hNew - bf2f(hi_));
            if (gather && t == lenS[row] - 1)
                friend_last[(size_t)sidS[row] * HD + j] = hNew;
        }
    };

    auto stageWrite = [&](const float4* sx) {
#pragma unroll
        for (int r = 0; r < 4; r++) {
            int row = wv * 4 + r;
            float vals[4] = { sx[r].x, sx[r].y, sx[r].z, sx[r].w };
            u16x4 hi4, lo4;
#pragma unroll
            for (int e2 = 0; e2 < 4; e2++) {
                unsigned short h_ = f2bf_rne(vals[e2]);
                hi4[e2] = h_;
                lo4[e2] = f2bf_rne(vals[e2] - bf2f(h_));
            }
            *(u16x4*)&Xhi[row][lane * 4] = hi4;
            *(u16x4*)&Xlo[row][lane * 4] = lo4;
        }
    };

    // stage x(0)
    {
        float4 sx[4];
#pragma unroll
        for (int r = 0; r < 4; r++)
            sx[r] = ((const float4*)(friend_x + ((size_t)srow[r] * LL) * HD))[lane];
        stageWrite(sx);
    }
    __syncthreads();

    // per-wave weight bases: (wv*2+l)*98304 ; +49152 for the m-phase
    const unsigned short* pw0 = wpk + (size_t)(wv * 2 + 0) * 98304 + (size_t)lane * 8;
    const unsigned short* pw1 = wpk + (size_t)(wv * 2 + 1) * 98304 + (size_t)lane * 8;

#pragma unroll 1
    for (int t = 0; t < maxlen; t++) {
        // issue next-step staging loads early (held in regs through layer 0)
        int tn = (t + 1 < maxlen) ? t + 1 : t;
        float4 sx[4];
#pragma unroll
        for (int r = 0; r < 4; r++)
            sx[r] = ((const float4*)(friend_x + ((size_t)srow[r] * LL + tn) * HD))[lane];

        // ---- Layer 0: gates = x(t)·Wih0 + h0·Whh0 ----
        f32x16 aR, aZ, aNi, aNh;
        initAcc(aR, b0R); initAcc(aZ, b0Z); initAcc(aNi, b0Ni); initAcc(aNh, b0Nh);
        halfMM(pw0,         &Xhi[0][0],  &Xlo[0][0],  aR, aZ, aNi);
        halfMM(pw0 + 49152, &H0hi[0][0], &H0lo[0][0], aR, aZ, aNh);
        __syncthreads();                       // B1: X/H0 reads complete
        epi(aR, aZ, aNi, aNh, H0hi, H0lo, false, t);
        stageWrite(sx);                        // write x(t+1)
        __syncthreads();                       // B2: h0(t) + x(t+1) visible
        // ---- Layer 1: gates = h0(t)·Wih1 + h1·Whh1 ----
        initAcc(aR, b1R); initAcc(aZ, b1Z); initAcc(aNi, b1Ni); initAcc(aNh, b1Nh);
        halfMM(pw1,         &H0hi[0][0], &H0lo[0][0], aR, aZ, aNi);
        halfMM(pw1 + 49152, &H1hi[0][0], &H1lo[0][0], aR, aZ, aNh);
        __syncthreads();                       // B3: H0/H1 reads complete
        epi(aR, aZ, aNi, aNh, H1hi, H1lo, true, t);
    }
}

// ---------------------------------------------------------------------------
// Fused: sf[n,h] = Wf[h,:256]·self_x[b] + Wf[h,256:]·fl[n]; v[n,h] = Wb[:,h]·sf[n,:]
// ---------------------------------------------------------------------------
__global__ __launch_bounds__(256)
void sfv_kernel(const float* __restrict__ self_x, const float* __restrict__ fl,
                const float* __restrict__ WfT, const float* __restrict__ Wb,
                float* __restrict__ vout) {
    __shared__ float S[256];
    __shared__ float T[256][33];   // phase1: fl^T [k][f]; phase2: sf^T [g][f]
    int b = blockIdx.x, tid = threadIdx.x;
    S[tid] = self_x[b * 256 + tid];
    for (int i = tid; i < 32 * 256; i += 256) {
        int f = i >> 8, k = i & 255;
        T[k][f] = fl[((size_t)(b * 32 + f)) * 256 + k];
    }
    __syncthreads();
    float acc0 = 0.f;
    for (int k = 0; k < 256; k++) acc0 += WfT[k * 256 + tid] * S[k];
    float acc[32];
#pragma unroll
    for (int f = 0; f < 32; f++) acc[f] = acc0;
    for (int k = 0; k < 256; k++) {
        float w = WfT[(256 + k) * 256 + tid];
#pragma unroll
        for (int f = 0; f < 32; f++) acc[f] += w * T[k][f];
    }
    __syncthreads();
#pragma unroll
    for (int f = 0; f < 32; f++) T[tid][f] = acc[f];   // sf^T into LDS
    __syncthreads();
    float av[32];
#pragma unroll
    for (int f = 0; f < 32; f++) av[f] = 0.f;
    for (int gg = 0; gg < 256; gg++) {
        float w = Wb[gg * 256 + tid];
#pragma unroll
        for (int f = 0; f < 32; f++) av[f] += w * T[gg][f];
    }
#pragma unroll
    for (int f = 0; f < 32; f++)
        vout[((size_t)(b * 32 + f)) * 256 + tid] = av[f];
}

// ---------------------------------------------------------------------------
// tf[n] = sum_s softplus(common_x[n,s,:]·v[n,:]) * exp(-time) * (s < clen)
// ---------------------------------------------------------------------------
__global__ __launch_bounds__(256)
void tf_kernel(const float* __restrict__ common_x, const float* __restrict__ common_time,
               const int* __restrict__ clen, const float* __restrict__ v,
               float* __restrict__ tf) {
    __shared__ float V[256];
    __shared__ float partial[4];
    int n = blockIdx.x, tid = threadIdx.x, wv = tid >> 6, lane = tid & 63;
    V[tid] = v[(size_t)n * 256 + tid];
    __syncthreads();
    float4 vv = ((const float4*)V)[lane];
    int cl = clen[n];
    float acc = 0.f;
    for (int s = wv; s < SS; s += 4) {
        float4 cx = ((const float4*)(common_x + ((size_t)n * SS + s) * HD))[lane];
        float d = cx.x * vv.x + cx.y * vv.y + cx.z * vv.z + cx.w * vv.w;
#pragma unroll
        for (int off = 32; off; off >>= 1) d += __shfl_xor(d, off);
        if (lane == 0 && s < cl) {
            float sp = (d > 20.f) ? d : log1pf(__expf(d));
            acc += sp * __expf(-common_time[n * SS + s]);
        }
    }
    if (lane == 0) partial[wv] = acc;
    __syncthreads();
    if (tid == 0) tf[n] = partial[0] + partial[1] + partial[2] + partial[3];
}

// ---------------------------------------------------------------------------
// softmax over padded MAXF (invalid logits exactly 0) + weighted sum.
// ---------------------------------------------------------------------------
__global__ __launch_bounds__(256)
void out_kernel(const float* __restrict__ tf, const int* __restrict__ fnum,
                const float* __restrict__ fl, float* __restrict__ out) {
    __shared__ float e[32];
    __shared__ float tfm[32];
    __shared__ float Zs;
    int b = blockIdx.x, tid = threadIdx.x;
    int nv = fnum[b];
    if (tid < 32) tfm[tid] = (tid < nv) ? tf[b * 32 + tid] : 0.f;
    __syncthreads();
    if (tid == 0) {
        float m = tfm[0];
        for (int f = 1; f < 32; f++) m = fmaxf(m, tfm[f]);
        float Z = 0.f;
        for (int f = 0; f < 32; f++) { e[f] = __expf(tfm[f] - m); Z += e[f]; }
        Zs = Z;
    }
    __syncthreads();
    float Zi = 1.f / Zs;
    float o = 0.f;
    for (int f = 0; f < nv; f++)
        o += e[f] * Zi * fl[((size_t)(b * 32 + f)) * 256 + tid];
    out[b * 256 + tid] = o;
}

// ---------------------------------------------------------------------------
extern "C" void kernel_launch(void* const* d_in, const int* in_sizes, int n_in,
                              void* d_out, int out_size, void* d_ws, size_t ws_size,
                              hipStream_t stream) {
    (void)in_sizes; (void)n_in; (void)out_size; (void)ws_size;
    const float* self_x      = (const float*)d_in[0];
    const float* common_x    = (const float*)d_in[1];
    const float* common_time = (const float*)d_in[2];
    const float* friend_x    = (const float*)d_in[3];
    const float* Wih0 = (const float*)d_in[4];
    const float* Whh0 = (const float*)d_in[5];
    const float* bih0 = (const float*)d_in[6];
    const float* bhh0 = (const float*)d_in[7];
    const float* Wih1 = (const float*)d_in[8];
    const float* Whh1 = (const float*)d_in[9];
    const float* bih1 = (const float*)d_in[10];
    const float* bhh1 = (const float*)d_in[11];
    const float* Wf   = (const float*)d_in[12];
    const float* Wb   = (const float*)d_in[13];
    const int* flen   = (const int*)d_in[14];
    const int* fnum   = (const int*)d_in[15];
    const int* clen   = (const int*)d_in[16];
    float* out = (float*)d_out;

    char* ws = (char*)d_ws;
    unsigned short* wpk = (unsigned short*)ws; ws += (size_t)1572864 * 2;
    float* WfT = (float*)ws;  ws += (size_t)512 * 256 * 4;
    int*   sid = (int*)ws;    ws += (size_t)2048 * 4;
    float* fl  = (float*)ws;  ws += (size_t)2048 * 256 * 4;
    float* vv  = (float*)ws;  ws += (size_t)2048 * 256 * 4;
    float* tf  = (float*)ws;  ws += (size_t)2048 * 4;

    pack_kernel<<<6656, 256, 0, stream>>>(Wih0, Whh0, Wih1, Whh1, Wf, wpk, WfT);
    sort_kernel<<<1, 256, 0, stream>>>(flen, sid);
    gru_kernel<<<NBLK, 512, 0, stream>>>(friend_x, flen, sid, wpk,
                                         bih0, bhh0, bih1, bhh1, fl);
    sfv_kernel<<<64, 256, 0, stream>>>(self_x, fl, WfT, Wb, vv);
    tf_kernel<<<2048, 256, 0, stream>>>(common_x, common_time, clen, vv, tf);
    out_kernel<<<64, 256, 0, stream>>>(tf, fnum, fl, out);
}

// Round 2
// 6556.443 us; speedup vs baseline: 1.0047x; 1.0047x over previous
//
#include <hip/hip_runtime.h>
#include <hip/hip_bf16.h>
#include <stdint.h>

// Problem constants
#define HD    256      // hidden
#define LL    50       // friend seq len
#define SS    50       // common seq len
#define NB    64       // batch
#define MAXF  32
#define NSEQ  2048     // NB*MAXF
#define MB    32       // sequences per block (one 32-row MFMA M-tile)
#define NBLK  64       // NSEQ/MB
#define XP    264      // padded LDS row (bf16 elems): 528B rows, 16B aligned

typedef __attribute__((ext_vector_type(8)))  short bf16x8;
typedef __attribute__((ext_vector_type(16))) float f32x16;
typedef __attribute__((ext_vector_type(4)))  unsigned short u16x4;

__device__ __forceinline__ f32x16 mfma32(bf16x8 a, bf16x8 b, f32x16 c) {
    return __builtin_amdgcn_mfma_f32_32x32x16_bf16(a, b, c, 0, 0, 0);
}

__device__ __forceinline__ unsigned short f2bf_rne(float f) {
    union { float f; uint32_t u; } v; v.f = f;
    uint32_t u = v.u;
    uint32_t r = u + 0x7FFFu + ((u >> 16) & 1u);
    return (unsigned short)(r >> 16);
}
__device__ __forceinline__ float bf2f(unsigned short b) {
    union { float f; uint32_t u; } v; v.u = ((uint32_t)b) << 16;
    return v.f;
}

// ---------------------------------------------------------------------------
// Pack weights -> per-wave MFMA 32x32x16 fragment stream + Wf^T.
// 8-wave layout: wpk index = ((((wv*2+l)*2 + m)*16 + ks)*6 + fr)*512 + lane*8 + j
//   fr = gate*2 + plane  (gate r/z/n, plane hi/lo)
//   W row n = gate*256 + wv*32 + (lane&31)     (wave wv owns cols [32wv,32wv+32))
//   k       = ks*16 + (lane>>5)*8 + j
// ---------------------------------------------------------------------------
__global__ void pack_kernel(const float* __restrict__ Wih0, const float* __restrict__ Whh0,
                            const float* __restrict__ Wih1, const float* __restrict__ Whh1,
                            const float* __restrict__ Wf,
                            unsigned short* __restrict__ wpk,
                            float* __restrict__ WfT) {
    int idx = blockIdx.x * blockDim.x + threadIdx.x;
    const int TOTW = 1572864;
    if (idx < TOTW) {
        int j    = idx & 7;
        int lane = (idx >> 3) & 63;
        int fr   = (idx >> 9) % 6;
        int t2   = (idx >> 9) / 6;           // ((wv*2+l)*2+m)*16+ks
        int ks   = t2 & 15;
        int m    = (t2 >> 4) & 1;
        int l    = (t2 >> 5) & 1;
        int wvv  = t2 >> 6;                  // 0..7
        int gate = fr >> 1, plane = fr & 1;
        const float* W = (l == 0) ? (m == 0 ? Wih0 : Whh0)
                                  : (m == 0 ? Wih1 : Whh1);
        int n = gate * 256 + wvv * 32 + (lane & 31);
        int k = ks * 16 + (lane >> 5) * 8 + j;
        float v = W[n * HD + k];
        unsigned short hi = f2bf_rne(v);
        wpk[idx] = plane ? f2bf_rne(v - bf2f(hi)) : hi;
    } else {
        int idx2 = idx - TOTW;
        if (idx2 < 512 * 256) {              // WfT[k][h] = Wf[h][k]
            int k = idx2 >> 8; int h = idx2 & 255;
            WfT[k * 256 + h] = Wf[h * 512 + k];
        }
    }
}

// ---------------------------------------------------------------------------
// Counting sort of the 2048 sequences by friend_len (1..50), ascending.
// ---------------------------------------------------------------------------
__global__ void sort_kernel(const int* __restrict__ flen, int* __restrict__ sid) {
    __shared__ int hist[64];
    __shared__ int offs[64];
    int tid = threadIdx.x;
    if (tid < 64) hist[tid] = 0;
    __syncthreads();
    for (int i = tid; i < NSEQ; i += blockDim.x) atomicAdd(&hist[flen[i]], 1);
    __syncthreads();
    if (tid == 0) {
        int acc = 0;
        for (int v = 1; v <= 50; v++) { offs[v] = acc; acc += hist[v]; }
    }
    __syncthreads();
    for (int i = tid; i < NSEQ; i += blockDim.x) {
        int pos = atomicAdd(&offs[flen[i]], 1);
        sid[pos] = i;
    }
}

// ---------------------------------------------------------------------------
// Fused 2-layer GRU. 512 threads = 8 waves, EXACTLY 2 waves/SIMD pinned via
// launch_bounds(512,2)+waves_per_eu(2,2): per-wave budget 256 VGPRs (512-reg
// SIMD file / 2), which holds the 4-buffer weight rotation without spilling.
// Round-1 failed because waves_per_eu(2) (floor only) let the allocator pick
// a 128-reg budget -> 2GB scratch spill traffic. Wave w owns gate columns
// [32w,32w+32). Split-bf16 (hi+lo) 3-term MFMA. Lookahead-3 weight prefetch.
// ---------------------------------------------------------------------------
__global__ __launch_bounds__(512, 2) __attribute__((amdgpu_waves_per_eu(2, 2)))
void gru_kernel(const float* __restrict__ friend_x,
                const int* __restrict__ flen,
                const int* __restrict__ sid,
                const unsigned short* __restrict__ wpk,
                const float* __restrict__ bih0, const float* __restrict__ bhh0,
                const float* __restrict__ bih1, const float* __restrict__ bhh1,
                float* __restrict__ friend_last) {
    __shared__ __align__(16) unsigned short Xhi[MB][XP],  Xlo[MB][XP];
    __shared__ __align__(16) unsigned short H0hi[MB][XP], H0lo[MB][XP];
    __shared__ __align__(16) unsigned short H1hi[MB][XP], H1lo[MB][XP];
    __shared__ int sidS[MB], lenS[MB];

    const int tid  = threadIdx.x;
    const int g    = blockIdx.x;
    const int wv   = tid >> 6;          // 0..7
    const int lane = tid & 63;
    const int l31  = lane & 31;
    const int half = lane >> 5;

    if (tid < MB) {
        int s_ = sid[g * MB + tid];
        sidS[tid] = s_;
        lenS[tid] = flen[s_];
    }
    for (int i = tid; i < MB * XP / 2; i += 512) {
        ((uint32_t*)&H0hi[0][0])[i] = 0; ((uint32_t*)&H0lo[0][0])[i] = 0;
        ((uint32_t*)&H1hi[0][0])[i] = 0; ((uint32_t*)&H1lo[0][0])[i] = 0;
    }
    __syncthreads();

    int maxlen = 0;
#pragma unroll
    for (int s = 0; s < MB; s++) maxlen = max(maxlen, lenS[s]);

    const int j0 = wv * 32 + l31;       // this lane's gate column

    // biases (acc-init values); n-gate input/hidden kept separate
    float b0R  = bih0[j0] + bhh0[j0];
    float b0Z  = bih0[256 + j0] + bhh0[256 + j0];
    float b0Ni = bih0[512 + j0];
    float b0Nh = bhh0[512 + j0];
    float b1R  = bih1[j0] + bhh1[j0];
    float b1Z  = bih1[256 + j0] + bhh1[256 + j0];
    float b1Ni = bih1[512 + j0];
    float b1Nh = bhh1[512 + j0];

    int srow[4];                        // staged sequence ids (rows wv*4..wv*4+3)
#pragma unroll
    for (int r = 0; r < 4; r++) srow[r] = sidS[wv * 4 + r];

    const int fragBase = l31 * XP + half * 8;

    auto loadB6 = [&](bf16x8* B, const unsigned short* p) {
#pragma unroll
        for (int f = 0; f < 6; f++) B[f] = *(const bf16x8*)(p + f * 512);
    };

    // 9 MFMAs: one K=16 step for this wave's 32-col subtile of all 3 gates
    auto compute9 = [&](const bf16x8* B, bf16x8 ah, bf16x8 al,
                        f32x16& aRs, f32x16& aZs, f32x16& aNs) {
        aRs = mfma32(ah, B[0], aRs);
        aRs = mfma32(al, B[0], aRs);
        aRs = mfma32(ah, B[1], aRs);
        aZs = mfma32(ah, B[2], aZs);
        aZs = mfma32(al, B[2], aZs);
        aZs = mfma32(ah, B[3], aZs);
        aNs = mfma32(ah, B[4], aNs);
        aNs = mfma32(al, B[4], aNs);
        aNs = mfma32(ah, B[5], aNs);
    };

    // one m-phase (16 K-steps) of a layer: A from (Ah,Al), weights at pm.
    // 4-buffer rotation: each batch is loaded 3 compute9s (~216cy) before use.
    auto halfMM = [&](const unsigned short* pm,
                      const unsigned short* Ah_, const unsigned short* Al_,
                      f32x16& aRs, f32x16& aZs, f32x16& aNs) {
        bf16x8 B0[6], B1[6], B2[6], B3[6];
        loadB6(B0, pm);
        loadB6(B1, pm + 3072);
        loadB6(B2, pm + 6144);
        loadB6(B3, pm + 9216);
        bf16x8 ahA = *(const bf16x8*)(Ah_ + fragBase);
        bf16x8 alA = *(const bf16x8*)(Al_ + fragBase);
        bf16x8 ahB, alB;
#pragma unroll
        for (int base = 0; base < 16; base += 4) {
            ahB = *(const bf16x8*)(Ah_ + fragBase + (base + 1) * 16);
            alB = *(const bf16x8*)(Al_ + fragBase + (base + 1) * 16);
            compute9(B0, ahA, alA, aRs, aZs, aNs);
            if (base + 4 < 16) loadB6(B0, pm + (size_t)(base + 4) * 3072);
            ahA = *(const bf16x8*)(Ah_ + fragBase + (base + 2) * 16);
            alA = *(const bf16x8*)(Al_ + fragBase + (base + 2) * 16);
            compute9(B1, ahB, alB, aRs, aZs, aNs);
            if (base + 5 < 16) loadB6(B1, pm + (size_t)(base + 5) * 3072);
            ahB = *(const bf16x8*)(Ah_ + fragBase + (base + 3) * 16);
            alB = *(const bf16x8*)(Al_ + fragBase + (base + 3) * 16);
            compute9(B2, ahA, alA, aRs, aZs, aNs);
            if (base + 6 < 16) loadB6(B2, pm + (size_t)(base + 6) * 3072);
            {
                const int kn = (base + 4 < 16) ? base + 4 : 15;  // clamped prefetch
                ahA = *(const bf16x8*)(Ah_ + fragBase + kn * 16);
                alA = *(const bf16x8*)(Al_ + fragBase + kn * 16);
            }
            compute9(B3, ahB, alB, aRs, aZs, aNs);
            if (base + 7 < 16) loadB6(B3, pm + (size_t)(base + 7) * 3072);
        }
    };

    auto initAcc = [&](f32x16& a, float b) {
        f32x16 v;
#pragma unroll
        for (int i = 0; i < 16; i++) v[i] = b;
        a = v;
    };

    // gate epilogue; C-layout: col = lane&31, row = (reg&3)+8*(reg>>2)+4*half.
    // hidden carry reconstructed as hi+lo from LDS (err ~2^-25, negligible).
    auto epi = [&](f32x16& aRs, f32x16& aZs, f32x16& aNis, f32x16& aNhs,
                   unsigned short (*Ohi)[XP], unsigned short (*Olo)[XP],
                   bool gather, int t) {
        const int j = j0;
#pragma unroll
        for (int rg = 0; rg < 16; rg++) {
            const int row = (rg & 3) + ((rg >> 2) << 3) + (half << 2);
            float hOld = bf2f(Ohi[row][j]) + bf2f(Olo[row][j]);
            float rr = 1.f / (1.f + __expf(-aRs[rg]));
            float zz = 1.f / (1.f + __expf(-aZs[rg]));
            float nx = aNis[rg] + rr * aNhs[rg];
            float e  = __expf(-2.f * fabsf(nx));
            float th = 1.f - 2.f * e / (1.f + e);
            th = (nx < 0.f) ? -th : th;
            float hNew = (1.f - zz) * th + zz * hOld;
            unsigned short hi_ = f2bf_rne(hNew);
            Ohi[row][j] = hi_;
            Olo[row][j] = f2bf_rne(hNew - bf2f(hi_));
            if (gather && t == lenS[row] - 1)
                friend_last[(size_t)sidS[row] * HD + j] = hNew;
        }
    };

    auto stageWrite = [&](const float4* sx) {
#pragma unroll
        for (int r = 0; r < 4; r++) {
            int row = wv * 4 + r;
            float vals[4] = { sx[r].x, sx[r].y, sx[r].z, sx[r].w };
            u16x4 hi4, lo4;
#pragma unroll
            for (int e2 = 0; e2 < 4; e2++) {
                unsigned short h_ = f2bf_rne(vals[e2]);
                hi4[e2] = h_;
                lo4[e2] = f2bf_rne(vals[e2] - bf2f(h_));
            }
            *(u16x4*)&Xhi[row][lane * 4] = hi4;
            *(u16x4*)&Xlo[row][lane * 4] = lo4;
        }
    };

    // stage x(0)
    {
        float4 sx[4];
#pragma unroll
        for (int r = 0; r < 4; r++)
            sx[r] = ((const float4*)(friend_x + ((size_t)srow[r] * LL) * HD))[lane];
        stageWrite(sx);
    }
    __syncthreads();

    // per-wave weight bases: (wv*2+l)*98304 ; +49152 for the m-phase
    const unsigned short* pw0 = wpk + (size_t)(wv * 2 + 0) * 98304 + (size_t)lane * 8;
    const unsigned short* pw1 = wpk + (size_t)(wv * 2 + 1) * 98304 + (size_t)lane * 8;

#pragma unroll 1
    for (int t = 0; t < maxlen; t++) {
        // issue next-step staging loads early (held in regs through layer 0)
        int tn = (t + 1 < maxlen) ? t + 1 : t;
        float4 sx[4];
#pragma unroll
        for (int r = 0; r < 4; r++)
            sx[r] = ((const float4*)(friend_x + ((size_t)srow[r] * LL + tn) * HD))[lane];

        // ---- Layer 0: gates = x(t)·Wih0 + h0·Whh0 ----
        f32x16 aR, aZ, aNi, aNh;
        initAcc(aR, b0R); initAcc(aZ, b0Z); initAcc(aNi, b0Ni); initAcc(aNh, b0Nh);
        halfMM(pw0,         &Xhi[0][0],  &Xlo[0][0],  aR, aZ, aNi);
        halfMM(pw0 + 49152, &H0hi[0][0], &H0lo[0][0], aR, aZ, aNh);
        __syncthreads();                       // B1: X/H0 reads complete
        epi(aR, aZ, aNi, aNh, H0hi, H0lo, false, t);
        stageWrite(sx);                        // write x(t+1)
        __syncthreads();                       // B2: h0(t) + x(t+1) visible
        // ---- Layer 1: gates = h0(t)·Wih1 + h1·Whh1 ----
        initAcc(aR, b1R); initAcc(aZ, b1Z); initAcc(aNi, b1Ni); initAcc(aNh, b1Nh);
        halfMM(pw1,         &H0hi[0][0], &H0lo[0][0], aR, aZ, aNi);
        halfMM(pw1 + 49152, &H1hi[0][0], &H1lo[0][0], aR, aZ, aNh);
        __syncthreads();                       // B3: H0/H1 reads complete
        epi(aR, aZ, aNi, aNh, H1hi, H1lo, true, t);
    }
}

// ---------------------------------------------------------------------------
// Fused: sf[n,h] = Wf[h,:256]·self_x[b] + Wf[h,256:]·fl[n]; v[n,h] = Wb[:,h]·sf[n,:]
// ---------------------------------------------------------------------------
__global__ __launch_bounds__(256)
void sfv_kernel(const float* __restrict__ self_x, const float* __restrict__ fl,
                const float* __restrict__ WfT, const float* __restrict__ Wb,
                float* __restrict__ vout) {
    __shared__ float S[256];
    __shared__ float T[256][33];   // phase1: fl^T [k][f]; phase2: sf^T [g][f]
    int b = blockIdx.x, tid = threadIdx.x;
    S[tid] = self_x[b * 256 + tid];
    for (int i = tid; i < 32 * 256; i += 256) {
        int f = i >> 8, k = i & 255;
        T[k][f] = fl[((size_t)(b * 32 + f)) * 256 + k];
    }
    __syncthreads();
    float acc0 = 0.f;
    for (int k = 0; k < 256; k++) acc0 += WfT[k * 256 + tid] * S[k];
    float acc[32];
#pragma unroll
    for (int f = 0; f < 32; f++) acc[f] = acc0;
    for (int k = 0; k < 256; k++) {
        float w = WfT[(256 + k) * 256 + tid];
#pragma unroll
        for (int f = 0; f < 32; f++) acc[f] += w * T[k][f];
    }
    __syncthreads();
#pragma unroll
    for (int f = 0; f < 32; f++) T[tid][f] = acc[f];   // sf^T into LDS
    __syncthreads();
    float av[32];
#pragma unroll
    for (int f = 0; f < 32; f++) av[f] = 0.f;
    for (int gg = 0; gg < 256; gg++) {
        float w = Wb[gg * 256 + tid];
#pragma unroll
        for (int f = 0; f < 32; f++) av[f] += w * T[gg][f];
    }
#pragma unroll
    for (int f = 0; f < 32; f++)
        vout[((size_t)(b * 32 + f)) * 256 + tid] = av[f];
}

// ---------------------------------------------------------------------------
// tf[n] = sum_s softplus(common_x[n,s,:]·v[n,:]) * exp(-time) * (s < clen)
// ---------------------------------------------------------------------------
__global__ __launch_bounds__(256)
void tf_kernel(const float* __restrict__ common_x, const float* __restrict__ common_time,
               const int* __restrict__ clen, const float* __restrict__ v,
               float* __restrict__ tf) {
    __shared__ float V[256];
    __shared__ float partial[4];
    int n = blockIdx.x, tid = threadIdx.x, wv = tid >> 6, lane = tid & 63;
    V[tid] = v[(size_t)n * 256 + tid];
    __syncthreads();
    float4 vv = ((const float4*)V)[lane];
    int cl = clen[n];
    float acc = 0.f;
    for (int s = wv; s < SS; s += 4) {
        float4 cx = ((const float4*)(common_x + ((size_t)n * SS + s) * HD))[lane];
        float d = cx.x * vv.x + cx.y * vv.y + cx.z * vv.z + cx.w * vv.w;
#pragma unroll
        for (int off = 32; off; off >>= 1) d += __shfl_xor(d, off);
        if (lane == 0 && s < cl) {
            float sp = (d > 20.f) ? d : log1pf(__expf(d));
            acc += sp * __expf(-common_time[n * SS + s]);
        }
    }
    if (lane == 0) partial[wv] = acc;
    __syncthreads();
    if (tid == 0) tf[n] = partial[0] + partial[1] + partial[2] + partial[3];
}

// ---------------------------------------------------------------------------
// softmax over padded MAXF (invalid logits exactly 0) + weighted sum.
// ---------------------------------------------------------------------------
__global__ __launch_bounds__(256)
void out_kernel(const float* __restrict__ tf, const int* __restrict__ fnum,
                const float* __restrict__ fl, float* __restrict__ out) {
    __shared__ float e[32];
    __shared__ float tfm[32];
    __shared__ float Zs;
    int b = blockIdx.x, tid = threadIdx.x;
    int nv = fnum[b];
    if (tid < 32) tfm[tid] = (tid < nv) ? tf[b * 32 + tid] : 0.f;
    __syncthreads();
    if (tid == 0) {
        float m = tfm[0];
        for (int f = 1; f < 32; f++) m = fmaxf(m, tfm[f]);
        float Z = 0.f;
        for (int f = 0; f < 32; f++) { e[f] = __expf(tfm[f] - m); Z += e[f]; }
        Zs = Z;
    }
    __syncthreads();
    float Zi = 1.f / Zs;
    float o = 0.f;
    for (int f = 0; f < nv; f++)
        o += e[f] * Zi * fl[((size_t)(b * 32 + f)) * 256 + tid];
    out[b * 256 + tid] = o;
}

// ---------------------------------------------------------------------------
extern "C" void kernel_launch(void* const* d_in, const int* in_sizes, int n_in,
                              void* d_out, int out_size, void* d_ws, size_t ws_size,
                              hipStream_t stream) {
    (void)in_sizes; (void)n_in; (void)out_size; (void)ws_size;
    const float* self_x      = (const float*)d_in[0];
    const float* common_x    = (const float*)d_in[1];
    const float* common_time = (const float*)d_in[2];
    const float* friend_x    = (const float*)d_in[3];
    const float* Wih0 = (const float*)d_in[4];
    const float* Whh0 = (const float*)d_in[5];
    const float* bih0 = (const float*)d_in[6];
    const float* bhh0 = (const float*)d_in[7];
    const float* Wih1 = (const float*)d_in[8];
    const float* Whh1 = (const float*)d_in[9];
    const float* bih1 = (const float*)d_in[10];
    const float* bhh1 = (const float*)d_in[11];
    const float* Wf   = (const float*)d_in[12];
    const float* Wb   = (const float*)d_in[13];
    const int* flen   = (const int*)d_in[14];
    const int* fnum   = (const int*)d_in[15];
    const int* clen   = (const int*)d_in[16];
    float* out = (float*)d_out;

    char* ws = (char*)d_ws;
    unsigned short* wpk = (unsigned short*)ws; ws += (size_t)1572864 * 2;
    float* WfT = (float*)ws;  ws += (size_t)512 * 256 * 4;
    int*   sid = (int*)ws;    ws += (size_t)2048 * 4;
    float* fl  = (float*)ws;  ws += (size_t)2048 * 256 * 4;
    float* vv  = (float*)ws;  ws += (size_t)2048 * 256 * 4;
    float* tf  = (float*)ws;  ws += (size_t)2048 * 4;

    pack_kernel<<<6656, 256, 0, stream>>>(Wih0, Whh0, Wih1, Whh1, Wf, wpk, WfT);
    sort_kernel<<<1, 256, 0, stream>>>(flen, sid);
    gru_kernel<<<NBLK, 512, 0, stream>>>(friend_x, flen, sid, wpk,
                                         bih0, bhh0, bih1, bhh1, fl);
    sfv_kernel<<<64, 256, 0, stream>>>(self_x, fl, WfT, Wb, vv);
    tf_kernel<<<2048, 256, 0, stream>>>(common_x, common_time, clen, vv, tf);
    out_kernel<<<64, 256, 0, stream>>>(tf, fnum, fl, out);
}

// Round 3
// 2524.262 us; speedup vs baseline: 2.6095x; 2.5974x over previous
//
#include <hip/hip_runtime.h>
#include <hip/hip_bf16.h>
#include <stdint.h>

// Problem constants
#define HD    256      // hidden
#define LL    50       // friend seq len
#define SS    50       // common seq len
#define NB    64       // batch
#define MAXF  32
#define NSEQ  2048     // NB*MAXF
#define MB    32       // sequences per block (one 32-row MFMA M-tile)
#define NBLK  64       // NSEQ/MB
#define XP    264      // padded LDS row (bf16 elems): 528B rows, 16B aligned

typedef __attribute__((ext_vector_type(8)))  short bf16x8;
typedef __attribute__((ext_vector_type(16))) float f32x16;
typedef __attribute__((ext_vector_type(4)))  unsigned short u16x4;

__device__ __forceinline__ f32x16 mfma32(bf16x8 a, bf16x8 b, f32x16 c) {
    return __builtin_amdgcn_mfma_f32_32x32x16_bf16(a, b, c, 0, 0, 0);
}

__device__ __forceinline__ unsigned short f2bf_rne(float f) {
    union { float f; uint32_t u; } v; v.f = f;
    uint32_t u = v.u;
    uint32_t r = u + 0x7FFFu + ((u >> 16) & 1u);
    return (unsigned short)(r >> 16);
}
__device__ __forceinline__ float bf2f(unsigned short b) {
    union { float f; uint32_t u; } v; v.u = ((uint32_t)b) << 16;
    return v.f;
}

// ---------------------------------------------------------------------------
// Pack weights -> per-wave MFMA 32x32x16 fragment stream + Wf^T.
// 8-wave layout: wpk index = ((((wv*2+l)*2 + m)*16 + ks)*6 + fr)*512 + lane*8 + j
//   fr = gate*2 + plane  (gate r/z/n, plane hi/lo)
//   W row n = gate*256 + wv*32 + (lane&31)     (wave wv owns cols [32wv,32wv+32))
//   k       = ks*16 + (lane>>5)*8 + j
// ---------------------------------------------------------------------------
__global__ void pack_kernel(const float* __restrict__ Wih0, const float* __restrict__ Whh0,
                            const float* __restrict__ Wih1, const float* __restrict__ Whh1,
                            const float* __restrict__ Wf,
                            unsigned short* __restrict__ wpk,
                            float* __restrict__ WfT) {
    int idx = blockIdx.x * blockDim.x + threadIdx.x;
    const int TOTW = 1572864;
    if (idx < TOTW) {
        int j    = idx & 7;
        int lane = (idx >> 3) & 63;
        int fr   = (idx >> 9) % 6;
        int t2   = (idx >> 9) / 6;           // ((wv*2+l)*2+m)*16+ks
        int ks   = t2 & 15;
        int m    = (t2 >> 4) & 1;
        int l    = (t2 >> 5) & 1;
        int wvv  = t2 >> 6;                  // 0..7
        int gate = fr >> 1, plane = fr & 1;
        const float* W = (l == 0) ? (m == 0 ? Wih0 : Whh0)
                                  : (m == 0 ? Wih1 : Whh1);
        int n = gate * 256 + wvv * 32 + (lane & 31);
        int k = ks * 16 + (lane >> 5) * 8 + j;
        float v = W[n * HD + k];
        unsigned short hi = f2bf_rne(v);
        wpk[idx] = plane ? f2bf_rne(v - bf2f(hi)) : hi;
    } else {
        int idx2 = idx - TOTW;
        if (idx2 < 512 * 256) {              // WfT[k][h] = Wf[h][k]
            int k = idx2 >> 8; int h = idx2 & 255;
            WfT[k * 256 + h] = Wf[h * 512 + k];
        }
    }
}

// ---------------------------------------------------------------------------
// Counting sort of the 2048 sequences by friend_len (1..50), ascending.
// ---------------------------------------------------------------------------
__global__ void sort_kernel(const int* __restrict__ flen, int* __restrict__ sid) {
    __shared__ int hist[64];
    __shared__ int offs[64];
    int tid = threadIdx.x;
    if (tid < 64) hist[tid] = 0;
    __syncthreads();
    for (int i = tid; i < NSEQ; i += blockDim.x) atomicAdd(&hist[flen[i]], 1);
    __syncthreads();
    if (tid == 0) {
        int acc = 0;
        for (int v = 1; v <= 50; v++) { offs[v] = acc; acc += hist[v]; }
    }
    __syncthreads();
    for (int i = tid; i < NSEQ; i += blockDim.x) {
        int pos = atomicAdd(&offs[flen[i]], 1);
        sid[pos] = i;
    }
}

// ---------------------------------------------------------------------------
// Fused 2-layer GRU. 512 threads = 8 waves (2 waves/SIMD). gfx950 splits the
// per-wave budget into 128 arch-VGPR + 128 AGPR at 2 waves/EU; rounds 1-2
// spilled because the main loop needed ~160 arch regs (4 weight buffers).
// This version uses 2 weight buffers (48 regs) -> ~110 arch regs, no spill.
// Accumulators (64) live in AGPRs. Wave w owns gate columns [32w,32w+32).
// Split-bf16 (hi+lo) 3-term MFMA. Hidden carry reconstructed from LDS planes.
// ---------------------------------------------------------------------------
__global__ __launch_bounds__(512, 2) __attribute__((amdgpu_waves_per_eu(2, 2)))
void gru_kernel(const float* __restrict__ friend_x,
                const int* __restrict__ flen,
                const int* __restrict__ sid,
                const unsigned short* __restrict__ wpk,
                const float* __restrict__ bih0, const float* __restrict__ bhh0,
                const float* __restrict__ bih1, const float* __restrict__ bhh1,
                float* __restrict__ friend_last) {
    __shared__ __align__(16) unsigned short Xhi[MB][XP],  Xlo[MB][XP];
    __shared__ __align__(16) unsigned short H0hi[MB][XP], H0lo[MB][XP];
    __shared__ __align__(16) unsigned short H1hi[MB][XP], H1lo[MB][XP];
    __shared__ int sidS[MB], lenS[MB];

    const int tid  = threadIdx.x;
    const int g    = blockIdx.x;
    const int wv   = tid >> 6;          // 0..7
    const int lane = tid & 63;
    const int l31  = lane & 31;
    const int half = lane >> 5;

    if (tid < MB) {
        int s_ = sid[g * MB + tid];
        sidS[tid] = s_;
        lenS[tid] = flen[s_];
    }
    for (int i = tid; i < MB * XP / 2; i += 512) {
        ((uint32_t*)&H0hi[0][0])[i] = 0; ((uint32_t*)&H0lo[0][0])[i] = 0;
        ((uint32_t*)&H1hi[0][0])[i] = 0; ((uint32_t*)&H1lo[0][0])[i] = 0;
    }
    __syncthreads();

    int maxlen = 0;
#pragma unroll
    for (int s = 0; s < MB; s++) maxlen = max(maxlen, lenS[s]);

    const int j0 = wv * 32 + l31;       // this lane's gate column

    // biases (acc-init values); n-gate input/hidden kept separate
    float b0R  = bih0[j0] + bhh0[j0];
    float b0Z  = bih0[256 + j0] + bhh0[256 + j0];
    float b0Ni = bih0[512 + j0];
    float b0Nh = bhh0[512 + j0];
    float b1R  = bih1[j0] + bhh1[j0];
    float b1Z  = bih1[256 + j0] + bhh1[256 + j0];
    float b1Ni = bih1[512 + j0];
    float b1Nh = bhh1[512 + j0];

    int srow[4];                        // staged sequence ids (rows wv*4..wv*4+3)
#pragma unroll
    for (int r = 0; r < 4; r++) srow[r] = sidS[wv * 4 + r];

    const int fragBase = l31 * XP + half * 8;

    auto loadB6 = [&](bf16x8* B, const unsigned short* p) {
#pragma unroll
        for (int f = 0; f < 6; f++) B[f] = *(const bf16x8*)(p + f * 512);
    };

    // 9 MFMAs: one K=16 step for this wave's 32-col subtile of all 3 gates.
    // Gate-interleaved order keeps dependent-MFMA distance >= 3.
    auto compute9 = [&](const bf16x8* B, bf16x8 ah, bf16x8 al,
                        f32x16& aRs, f32x16& aZs, f32x16& aNs) {
        aRs = mfma32(ah, B[0], aRs);
        aZs = mfma32(ah, B[2], aZs);
        aNs = mfma32(ah, B[4], aNs);
        aRs = mfma32(al, B[0], aRs);
        aZs = mfma32(al, B[2], aZs);
        aNs = mfma32(al, B[4], aNs);
        aRs = mfma32(ah, B[1], aRs);
        aZs = mfma32(ah, B[3], aZs);
        aNs = mfma32(ah, B[5], aNs);
    };

    // one m-phase (16 K-steps) of a layer: A from (Ah,Al), weights at pm.
    // 2-buffer ping-pong (48 arch VGPRs): lookahead 1 compute9 per buffer,
    // 12 loads in flight per wave -> 24 per SIMD at 2 waves/SIMD.
    auto halfMM = [&](const unsigned short* pm,
                      const unsigned short* Ah_, const unsigned short* Al_,
                      f32x16& aRs, f32x16& aZs, f32x16& aNs) {
        bf16x8 B0[6], B1[6];
        loadB6(B0, pm);
        loadB6(B1, pm + 3072);
        bf16x8 ahA = *(const bf16x8*)(Ah_ + fragBase);
        bf16x8 alA = *(const bf16x8*)(Al_ + fragBase);
        bf16x8 ahB, alB;
#pragma unroll 1
        for (int ks = 0; ks < 16; ks += 2) {
            ahB = *(const bf16x8*)(Ah_ + fragBase + (ks + 1) * 16);
            alB = *(const bf16x8*)(Al_ + fragBase + (ks + 1) * 16);
            compute9(B0, ahA, alA, aRs, aZs, aNs);
            if (ks + 2 < 16) {
                loadB6(B0, pm + (size_t)(ks + 2) * 3072);
                ahA = *(const bf16x8*)(Ah_ + fragBase + (ks + 2) * 16);
                alA = *(const bf16x8*)(Al_ + fragBase + (ks + 2) * 16);
            }
            compute9(B1, ahB, alB, aRs, aZs, aNs);
            if (ks + 3 < 16) loadB6(B1, pm + (size_t)(ks + 3) * 3072);
        }
    };

    auto initAcc = [&](f32x16& a, float b) {
        f32x16 v;
#pragma unroll
        for (int i = 0; i < 16; i++) v[i] = b;
        a = v;
    };

    // gate epilogue; C-layout: col = lane&31, row = (reg&3)+8*(reg>>2)+4*half.
    // hidden carry reconstructed as hi+lo from LDS (err ~2^-25, negligible).
    auto epi = [&](f32x16& aRs, f32x16& aZs, f32x16& aNis, f32x16& aNhs,
                   unsigned short (*Ohi)[XP], unsigned short (*Olo)[XP],
                   bool gather, int t) {
        const int j = j0;
#pragma unroll
        for (int rg = 0; rg < 16; rg++) {
            const int row = (rg & 3) + ((rg >> 2) << 3) + (half << 2);
            float hOld = bf2f(Ohi[row][j]) + bf2f(Olo[row][j]);
            float rr = 1.f / (1.f + __expf(-aRs[rg]));
            float zz = 1.f / (1.f + __expf(-aZs[rg]));
            float nx = aNis[rg] + rr * aNhs[rg];
            float e  = __expf(-2.f * fabsf(nx));
            float th = 1.f - 2.f * e / (1.f + e);
            th = (nx < 0.f) ? -th : th;
            float hNew = (1.f - zz) * th + zz * hOld;
            unsigned short hi_ = f2bf_rne(hNew);
            Ohi[row][j] = hi_;
            Olo[row][j] = f2bf_rne(hNew - bf2f(hi_));
            if (gather && t == lenS[row] - 1)
                friend_last[(size_t)sidS[row] * HD + j] = hNew;
        }
    };

    auto stageWrite = [&](const float4* sx) {
#pragma unroll
        for (int r = 0; r < 4; r++) {
            int row = wv * 4 + r;
            float vals[4] = { sx[r].x, sx[r].y, sx[r].z, sx[r].w };
            u16x4 hi4, lo4;
#pragma unroll
            for (int e2 = 0; e2 < 4; e2++) {
                unsigned short h_ = f2bf_rne(vals[e2]);
                hi4[e2] = h_;
                lo4[e2] = f2bf_rne(vals[e2] - bf2f(h_));
            }
            *(u16x4*)&Xhi[row][lane * 4] = hi4;
            *(u16x4*)&Xlo[row][lane * 4] = lo4;
        }
    };

    // stage x(0)
    {
        float4 sx[4];
#pragma unroll
        for (int r = 0; r < 4; r++)
            sx[r] = ((const float4*)(friend_x + ((size_t)srow[r] * LL) * HD))[lane];
        stageWrite(sx);
    }
    __syncthreads();

    // per-wave weight bases: (wv*2+l)*98304 ; +49152 for the m-phase
    const unsigned short* pw0 = wpk + (size_t)(wv * 2 + 0) * 98304 + (size_t)lane * 8;
    const unsigned short* pw1 = wpk + (size_t)(wv * 2 + 1) * 98304 + (size_t)lane * 8;

#pragma unroll 1
    for (int t = 0; t < maxlen; t++) {
        // issue next-step staging loads early (held in regs through layer 0)
        int tn = (t + 1 < maxlen) ? t + 1 : t;
        float4 sx[4];
#pragma unroll
        for (int r = 0; r < 4; r++)
            sx[r] = ((const float4*)(friend_x + ((size_t)srow[r] * LL + tn) * HD))[lane];

        // ---- Layer 0: gates = x(t)·Wih0 + h0·Whh0 ----
        f32x16 aR, aZ, aNi, aNh;
        initAcc(aR, b0R); initAcc(aZ, b0Z); initAcc(aNi, b0Ni); initAcc(aNh, b0Nh);
        halfMM(pw0,         &Xhi[0][0],  &Xlo[0][0],  aR, aZ, aNi);
        halfMM(pw0 + 49152, &H0hi[0][0], &H0lo[0][0], aR, aZ, aNh);
        __syncthreads();                       // B1: X/H0 reads complete
        epi(aR, aZ, aNi, aNh, H0hi, H0lo, false, t);
        stageWrite(sx);                        // write x(t+1)
        __syncthreads();                       // B2: h0(t) + x(t+1) visible
        // ---- Layer 1: gates = h0(t)·Wih1 + h1·Whh1 ----
        initAcc(aR, b1R); initAcc(aZ, b1Z); initAcc(aNi, b1Ni); initAcc(aNh, b1Nh);
        halfMM(pw1,         &H0hi[0][0], &H0lo[0][0], aR, aZ, aNi);
        halfMM(pw1 + 49152, &H1hi[0][0], &H1lo[0][0], aR, aZ, aNh);
        __syncthreads();                       // B3: H0/H1 reads complete
        epi(aR, aZ, aNi, aNh, H1hi, H1lo, true, t);
    }
}

// ---------------------------------------------------------------------------
// Fused: sf[n,h] = Wf[h,:256]·self_x[b] + Wf[h,256:]·fl[n]; v[n,h] = Wb[:,h]·sf[n,:]
// ---------------------------------------------------------------------------
__global__ __launch_bounds__(256)
void sfv_kernel(const float* __restrict__ self_x, const float* __restrict__ fl,
                const float* __restrict__ WfT, const float* __restrict__ Wb,
                float* __restrict__ vout) {
    __shared__ float S[256];
    __shared__ float T[256][33];   // phase1: fl^T [k][f]; phase2: sf^T [g][f]
    int b = blockIdx.x, tid = threadIdx.x;
    S[tid] = self_x[b * 256 + tid];
    for (int i = tid; i < 32 * 256; i += 256) {
        int f = i >> 8, k = i & 255;
        T[k][f] = fl[((size_t)(b * 32 + f)) * 256 + k];
    }
    __syncthreads();
    float acc0 = 0.f;
    for (int k = 0; k < 256; k++) acc0 += WfT[k * 256 + tid] * S[k];
    float acc[32];
#pragma unroll
    for (int f = 0; f < 32; f++) acc[f] = acc0;
    for (int k = 0; k < 256; k++) {
        float w = WfT[(256 + k) * 256 + tid];
#pragma unroll
        for (int f = 0; f < 32; f++) acc[f] += w * T[k][f];
    }
    __syncthreads();
#pragma unroll
    for (int f = 0; f < 32; f++) T[tid][f] = acc[f];   // sf^T into LDS
    __syncthreads();
    float av[32];
#pragma unroll
    for (int f = 0; f < 32; f++) av[f] = 0.f;
    for (int gg = 0; gg < 256; gg++) {
        float w = Wb[gg * 256 + tid];
#pragma unroll
        for (int f = 0; f < 32; f++) av[f] += w * T[gg][f];
    }
#pragma unroll
    for (int f = 0; f < 32; f++)
        vout[((size_t)(b * 32 + f)) * 256 + tid] = av[f];
}

// ---------------------------------------------------------------------------
// tf[n] = sum_s softplus(common_x[n,s,:]·v[n,:]) * exp(-time) * (s < clen)
// ---------------------------------------------------------------------------
__global__ __launch_bounds__(256)
void tf_kernel(const float* __restrict__ common_x, const float* __restrict__ common_time,
               const int* __restrict__ clen, const float* __restrict__ v,
               float* __restrict__ tf) {
    __shared__ float V[256];
    __shared__ float partial[4];
    int n = blockIdx.x, tid = threadIdx.x, wv = tid >> 6, lane = tid & 63;
    V[tid] = v[(size_t)n * 256 + tid];
    __syncthreads();
    float4 vv = ((const float4*)V)[lane];
    int cl = clen[n];
    float acc = 0.f;
    for (int s = wv; s < SS; s += 4) {
        float4 cx = ((const float4*)(common_x + ((size_t)n * SS + s) * HD))[lane];
        float d = cx.x * vv.x + cx.y * vv.y + cx.z * vv.z + cx.w * vv.w;
#pragma unroll
        for (int off = 32; off; off >>= 1) d += __shfl_xor(d, off);
        if (lane == 0 && s < cl) {
            float sp = (d > 20.f) ? d : log1pf(__expf(d));
            acc += sp * __expf(-common_time[n * SS + s]);
        }
    }
    if (lane == 0) partial[wv] = acc;
    __syncthreads();
    if (tid == 0) tf[n] = partial[0] + partial[1] + partial[2] + partial[3];
}

// ---------------------------------------------------------------------------
// softmax over padded MAXF (invalid logits exactly 0) + weighted sum.
// ---------------------------------------------------------------------------
__global__ __launch_bounds__(256)
void out_kernel(const float* __restrict__ tf, const int* __restrict__ fnum,
                const float* __restrict__ fl, float* __restrict__ out) {
    __shared__ float e[32];
    __shared__ float tfm[32];
    __shared__ float Zs;
    int b = blockIdx.x, tid = threadIdx.x;
    int nv = fnum[b];
    if (tid < 32) tfm[tid] = (tid < nv) ? tf[b * 32 + tid] : 0.f;
    __syncthreads();
    if (tid == 0) {
        float m = tfm[0];
        for (int f = 1; f < 32; f++) m = fmaxf(m, tfm[f]);
        float Z = 0.f;
        for (int f = 0; f < 32; f++) { e[f] = __expf(tfm[f] - m); Z += e[f]; }
        Zs = Z;
    }
    __syncthreads();
    float Zi = 1.f / Zs;
    float o = 0.f;
    for (int f = 0; f < nv; f++)
        o += e[f] * Zi * fl[((size_t)(b * 32 + f)) * 256 + tid];
    out[b * 256 + tid] = o;
}

// ---------------------------------------------------------------------------
extern "C" void kernel_launch(void* const* d_in, const int* in_sizes, int n_in,
                              void* d_out, int out_size, void* d_ws, size_t ws_size,
                              hipStream_t stream) {
    (void)in_sizes; (void)n_in; (void)out_size; (void)ws_size;
    const float* self_x      = (const float*)d_in[0];
    const float* common_x    = (const float*)d_in[1];
    const float* common_time = (const float*)d_in[2];
    const float* friend_x    = (const float*)d_in[3];
    const float* Wih0 = (const float*)d_in[4];
    const float* Whh0 = (const float*)d_in[5];
    const float* bih0 = (const float*)d_in[6];
    const float* bhh0 = (const float*)d_in[7];
    const float* Wih1 = (const float*)d_in[8];
    const float* Whh1 = (const float*)d_in[9];
    const float* bih1 = (const float*)d_in[10];
    const float* bhh1 = (const float*)d_in[11];
    const float* Wf   = (const float*)d_in[12];
    const float* Wb   = (const float*)d_in[13];
    const int* flen   = (const int*)d_in[14];
    const int* fnum   = (const int*)d_in[15];
    const int* clen   = (const int*)d_in[16];
    float* out = (float*)d_out;

    char* ws = (char*)d_ws;
    unsigned short* wpk = (unsigned short*)ws; ws += (size_t)1572864 * 2;
    float* WfT = (float*)ws;  ws += (size_t)512 * 256 * 4;
    int*   sid = (int*)ws;    ws += (size_t)2048 * 4;
    float* fl  = (float*)ws;  ws += (size_t)2048 * 256 * 4;
    float* vv  = (float*)ws;  ws += (size_t)2048 * 256 * 4;
    float* tf  = (float*)ws;  ws += (size_t)2048 * 4;

    pack_kernel<<<6656, 256, 0, stream>>>(Wih0, Whh0, Wih1, Whh1, Wf, wpk, WfT);
    sort_kernel<<<1, 256, 0, stream>>>(flen, sid);
    gru_kernel<<<NBLK, 512, 0, stream>>>(friend_x, flen, sid, wpk,
                                         bih0, bhh0, bih1, bhh1, fl);
    sfv_kernel<<<64, 256, 0, stream>>>(self_x, fl, WfT, Wb, vv);
    tf_kernel<<<2048, 256, 0, stream>>>(common_x, common_time, clen, vv, tf);
    out_kernel<<<64, 256, 0, stream>>>(tf, fnum, fl, out);
}